// Round 16
// baseline (225.598 us; speedup 1.0000x reference)
//
#include <hip/hip_runtime.h>
#include <hip/hip_bf16.h>

// Problem constants
#define BB 32
#define SS 256
#define DD 300
#define PDD 32
#define MM 66
#define FF 398      // D + PD + M
#define HH 6
#define G4 24       // 4*H
#define AA 12
#define L2E 1.4426950408889634f

__device__ __forceinline__ float fast_rcp(float x) { return __builtin_amdgcn_rcpf(x); }
__device__ __forceinline__ float bcast_lane(float x, int l) {
    return __int_as_float(__builtin_amdgcn_readlane(__float_as_int(x), l));
}
template<int CTRL>
__device__ __forceinline__ float quad_bcast(float v) {
    return __int_as_float(__builtin_amdgcn_mov_dpp(__float_as_int(v), CTRL, 0xf, 0xf, true));
}

// -------------------------------------------------------------------------
// Kernel 1 (v7): fused embed+concat+projection, all-LDS, 2-pos register tile.
// Block = 32 positions, 256 thr, grid 256 (1 block/CU). Thread = 2 pos x
// 3 cols: per q, 2 feat b128 + 3 W b128 for 24 fma (was 7 b128 / 24 fma).
// sW rows padded to 101 float4 (404 floats = 20 mod 32) -> the 16 col-group
// rows land on 8 distinct 4-bank starts x2 = 2-way access (free).
// Epilogue folds bias + the lstm's +-log2e gate prescale.
// -------------------------------------------------------------------------
#define EPB 32
__global__ __launch_bounds__(256) void k_embed_proj(
    const int* __restrict__ words, const int* __restrict__ pos,
    const float* __restrict__ morph, const float* __restrict__ wtab,
    const float* __restrict__ ptab,
    const float* __restrict__ Wxf, const float* __restrict__ bfv,
    const float* __restrict__ Wxb, const float* __restrict__ bbv,
    float* __restrict__ xgf, float* __restrict__ xgb)
{
    __shared__ float4 sF[100][33];      // 52.8 KB
    __shared__ float4 sW[48 * 101];     // 77.6 KB (row stride 101 float4)
    int t  = threadIdx.x;
    int p0 = blockIdx.x * EPB;

    for (int idx = t; idx < EPB * 75; idx += 256) {
        int p = idx / 75, q = idx % 75;
        sF[q][p] = *(const float4*)(wtab + (size_t)words[p0 + p] * DD + 4 * q);
    }
    {
        int idx = t;                    // EPB*8 = 256 exactly
        int p = idx / 8, q = idx % 8;
        sF[75 + q][p] = *(const float4*)(ptab + pos[p0 + p] * PDD + 4 * q);
    }
    for (int idx = t; idx < EPB * 17; idx += 256) {
        int p = idx / 17, mq = idx % 17;
        const float2* ms = (const float2*)(morph + (size_t)(p0 + p) * MM);
        float2 lo = ms[2 * mq];
        float2 hi = (mq < 16) ? ms[2 * mq + 1] : make_float2(0.f, 0.f);
        sF[83 + mq][p] = make_float4(lo.x, lo.y, hi.x, hi.y);
    }
    {
        float* sWf = (float*)sW;
        for (int idx = t; idx < FF * G4; idx += 256) {
            int k = idx / G4, j = idx % G4;
            sWf[j * 404 + k]        = Wxf[idx];
            sWf[(24 + j) * 404 + k] = Wxb[idx];
        }
        if (t < 2 * G4) {               // zero pad k = 398,399 (cols never read 400..403)
            int j = t >> 1, k = 398 + (t & 1);
            sWf[j * 404 + k] = 0.f; sWf[(24 + j) * 404 + k] = 0.f;
        }
    }
    __syncthreads();

    int cg = t & 15;                    // 3-col group: cols 3cg..3cg+2 (0..47)
    int pp = t >> 4;                    // positions pp and pp+16
    int c0 = 3 * cg;                    // group never straddles the 24 boundary
    int dir = c0 >= 24 ? 1 : 0;
    int jj  = c0 - dir * 24;
    const float4* W0 = sW + (size_t)(dir * 24 + jj + 0) * 101;
    const float4* W1 = sW + (size_t)(dir * 24 + jj + 1) * 101;
    const float4* W2 = sW + (size_t)(dir * 24 + jj + 2) * 101;

    float a00 = 0.f, a01 = 0.f, a02 = 0.f;
    float a10 = 0.f, a11 = 0.f, a12 = 0.f;
    #pragma unroll 4
    for (int q = 0; q < 100; ++q) {
        float4 f0 = sF[q][pp];
        float4 f1 = sF[q][pp + 16];
        float4 w0 = W0[q], w1 = W1[q], w2 = W2[q];
        a00 = fmaf(f0.x, w0.x, a00); a00 = fmaf(f0.y, w0.y, a00);
        a00 = fmaf(f0.z, w0.z, a00); a00 = fmaf(f0.w, w0.w, a00);
        a01 = fmaf(f0.x, w1.x, a01); a01 = fmaf(f0.y, w1.y, a01);
        a01 = fmaf(f0.z, w1.z, a01); a01 = fmaf(f0.w, w1.w, a01);
        a02 = fmaf(f0.x, w2.x, a02); a02 = fmaf(f0.y, w2.y, a02);
        a02 = fmaf(f0.z, w2.z, a02); a02 = fmaf(f0.w, w2.w, a02);
        a10 = fmaf(f1.x, w0.x, a10); a10 = fmaf(f1.y, w0.y, a10);
        a10 = fmaf(f1.z, w0.z, a10); a10 = fmaf(f1.w, w0.w, a10);
        a11 = fmaf(f1.x, w1.x, a11); a11 = fmaf(f1.y, w1.y, a11);
        a11 = fmaf(f1.z, w1.z, a11); a11 = fmaf(f1.w, w1.w, a11);
        a12 = fmaf(f1.x, w2.x, a12); a12 = fmaf(f1.y, w2.y, a12);
        a12 = fmaf(f1.z, w2.z, a12); a12 = fmaf(f1.w, w2.w, a12);
    }

    // epilogue: bias + lstm prescale (gate type uniform within a 3-col group)
    float kk = (jj >= 12 && jj < 18) ? 2.f * L2E : -L2E;
    const float* bias = dir ? bbv : bfv;
    float b0 = bias[jj], b1 = bias[jj + 1], b2 = bias[jj + 2];
    float* xg = dir ? xgb : xgf;
    float* o0 = xg + (size_t)(p0 + pp) * G4 + jj;
    float* o1 = xg + (size_t)(p0 + pp + 16) * G4 + jj;
    o0[0] = (a00 + b0) * kk; o0[1] = (a01 + b1) * kk; o0[2] = (a02 + b2) * kk;
    o1[0] = (a10 + b0) * kk; o1[1] = (a11 + b1) * kk; o1[2] = (a12 + b2) * kk;
}

// -------------------------------------------------------------------------
// Kernel 2 (R15-verbatim + counter zeroing): LSTM + uawa fused. Block = one
// batch, 2 waves = fwd/bwd chains on separate SIMDs. Epilogue computes
// ua/wa PRESCALED by 2*log2e. Block 0 also zeroes k_score's finisher
// counter (runs before k_score in stream order; no cross-call state).
// -------------------------------------------------------------------------
__global__ __launch_bounds__(128) void k_lstm_uawa(
    const float* __restrict__ xgf, const float* __restrict__ xgb,
    const float* __restrict__ Whf, const float* __restrict__ Whb,
    const float* __restrict__ Wu, const float* __restrict__ bu,
    const float* __restrict__ Ww, const float* __restrict__ bw,
    float* __restrict__ ua, float* __restrict__ wa, int* __restrict__ cnt)
{
    __shared__ float sxg[2][(SS + 8) * G4];   // 50.7 KB
    __shared__ float hbuf[2][SS * HH];        // 12 KB
    int b    = blockIdx.x;                    // 0..31
    int lane = threadIdx.x & 63;
    int dir  = __builtin_amdgcn_readfirstlane(threadIdx.x >> 6);

    if (b == 0 && threadIdx.x == 0) *cnt = 0;

    const float* xg = (dir ? xgb : xgf) + (size_t)b * SS * G4;
    const float* Wh = dir ? Whb : Whf;

    {
        const float4* src = (const float4*)xg;
        float4* dst = (float4*)sxg[dir];
        #pragma unroll
        for (int u = 0; u < 24; ++u) {
            int d = lane + u * 64;            // float4 index 0..1535
            int row = d / 6, c4 = d - row * 6;
            int drow = dir ? (SS - 1 - row) : row;
            dst[drow * 6 + c4] = src[d];
        }
        for (int g2 = lane; g2 < 8 * G4; g2 += 64) sxg[dir][SS * G4 + g2] = 0.f;
    }

    int g    = lane % G4;                   // gate slot 0..23
    int cell = g >> 2;                      // 0..5
    int type = g & 3;                       // 0=i 1=f 2=c 3=o
    int j    = type * HH + cell;            // keras column

    float kk = (type == 2) ? 2.f * L2E : -L2E;
    float wh[HH];
    #pragma unroll
    for (int m = 0; m < HH; ++m) wh[m] = Wh[m * G4 + j] * kk;
    float Bc = (type == 2) ? 1.f : 0.f;
    float Ac = (type == 2) ? -1.f : 1.f;

    float sh[HH];
    #pragma unroll
    for (int m = 0; m < HH; ++m) sh[m] = 0.f;
    float c = 0.f;
    bool wr = (lane < G4) && ((lane & 3) == 0);

    const float* xb = sxg[dir] + j;
    float* hb = hbuf[dir];

    float pg[4];
    #pragma unroll
    for (int sl = 0; sl < 4; ++sl) pg[sl] = xb[sl * G4];

    #pragma unroll 1
    for (int t = 0; t < SS; t += 4) {
        #pragma unroll
        for (int sl = 0; sl < 4; ++sl) {
            float x = pg[sl];
            pg[sl] = xb[(t + 4 + sl) * G4];      // guard rows cover the tail

            float aa  = fmaf(sh[1], wh[1], fmaf(sh[0], wh[0], x));
            float bb2 = fmaf(sh[3], wh[3], sh[2] * wh[2]);
            float cc2 = fmaf(sh[5], wh[5], sh[4] * wh[4]);
            x = (aa + bb2) + cc2;

            float e   = __builtin_amdgcn_exp2f(x);
            float val = fmaf(Bc, e, Ac) * fast_rcp(1.f + e);

            float vi = quad_bcast<0>(val);
            float vf = quad_bcast<85>(val);
            float vc = quad_bcast<170>(val);
            float vo = quad_bcast<255>(val);

            c = fmaf(vf, c, vi * vc);
            float ec = __builtin_amdgcn_exp2f(c * (2.f * L2E));
            float h  = (ec - 1.f) * fast_rcp(ec + 1.f) * vo;

            if (wr) hb[(t + sl) * HH + cell] = h;
            #pragma unroll
            for (int m = 0; m < HH; ++m) sh[m] = bcast_lane(h, 4 * m);
        }
    }
    __syncthreads();

    // epilogue: ua/wa (prescaled 2*log2e) for this batch's 256 positions.
    #pragma unroll
    for (int half = 0; half < 2; ++half) {
        int s = (int)threadIdx.x + half * 128;
        float r[AA];
        #pragma unroll
        for (int cc = 0; cc < HH; ++cc) {
            r[cc]      = hbuf[0][s * HH + cc];
            r[HH + cc] = hbuf[1][(SS - 1 - s) * HH + cc];
        }
        float au[AA], aw[AA];
        #pragma unroll
        for (int d = 0; d < AA; ++d) { au[d] = bu[d]; aw[d] = bw[d]; }
        #pragma unroll
        for (int e2 = 0; e2 < AA; ++e2) {
            #pragma unroll
            for (int d = 0; d < AA; ++d) {
                au[d] = fmaf(r[e2], Wu[e2 * AA + d], au[d]);
                aw[d] = fmaf(r[e2], Ww[e2 * AA + d], aw[d]);
            }
        }
        float* ou = ua + ((size_t)b * SS + s) * AA;
        float* ow = wa + ((size_t)b * SS + s) * AA;
        #pragma unroll
        for (int d4 = 0; d4 < 3; ++d4) {
            *(float4*)(ou + 4 * d4) = make_float4(au[4*d4] * (2.f*L2E), au[4*d4+1] * (2.f*L2E),
                                                  au[4*d4+2] * (2.f*L2E), au[4*d4+3] * (2.f*L2E));
            *(float4*)(ow + 4 * d4) = make_float4(aw[4*d4] * (2.f*L2E), aw[4*d4+1] * (2.f*L2E),
                                                  aw[4*d4+2] * (2.f*L2E), aw[4*d4+3] * (2.f*L2E));
        }
    }
}

// -------------------------------------------------------------------------
// Kernel 4 (v4): arc scores + FUSED loss finisher. 4 dependants per block
// (grid 2048), ua row loaded once and reused x4, exp2 tanh on prescaled
// inputs. After ce writes: device fence + atomic counter; the last block
// re-fences and does the fixed-order ce reduction (deterministic result
// regardless of which block finishes last).
// -------------------------------------------------------------------------
__global__ __launch_bounds__(256) void k_score(
    const float* __restrict__ ua, const float* __restrict__ wa,
    const float* __restrict__ v, const int* __restrict__ heads,
    float* __restrict__ out, float* __restrict__ ce, int* __restrict__ cnt)
{
    int blk = blockIdx.x;           // b*64 + ig
    int b   = blk >> 6;
    int i0  = (blk & 63) * 4;
    int j   = threadIdx.x;
    int w   = j >> 6;

    __shared__ float swa[4][AA], sv[AA];
    __shared__ float part[4][4];
    __shared__ int lastFlag;
    if (j < 4 * AA) swa[j / AA][j % AA] = wa[((size_t)b * SS + i0 + j / AA) * AA + j % AA];
    if (j < AA) sv[j] = v[j];
    __syncthreads();

    float sumv = 0.f;
    #pragma unroll
    for (int d = 0; d < AA; ++d) sumv += sv[d];

    const float* uj = ua + ((size_t)b * SS + j) * AA;
    float4 u0 = *(const float4*)(uj);
    float4 u1 = *(const float4*)(uj + 4);
    float4 u2 = *(const float4*)(uj + 8);
    float us[AA] = {u0.x, u0.y, u0.z, u0.w, u1.x, u1.y, u1.z, u1.w,
                    u2.x, u2.y, u2.z, u2.w};

    float sv_[4];
    #pragma unroll
    for (int ii = 0; ii < 4; ++ii) {
        int i = i0 + ii;
        float acc = 0.f;
        #pragma unroll
        for (int d = 0; d < AA; ++d) {
            float e_d = __builtin_amdgcn_exp2f(us[d] + swa[ii][d]);
            acc = fmaf(sv[d], fast_rcp(1.f + e_d), acc);
        }
        float s = fmaf(-2.f, acc, sumv);
        if (j == i) s = -10000.f;
        sv_[ii] = s;

        float e = __builtin_amdgcn_exp2f(s * L2E);
        if (i >= 1)
            out[1 + (((size_t)(i - 1) * BB + b) * SS + j)] = e;

        float r = e;
        #pragma unroll
        for (int off = 32; off > 0; off >>= 1) r += __shfl_xor(r, off, 64);
        if ((j & 63) == 0) part[ii][w] = r;
    }
    __syncthreads();

    #pragma unroll
    for (int ii = 0; ii < 4; ++ii) {
        int i = i0 + ii;
        float tot = part[ii][0] + part[ii][1] + part[ii][2] + part[ii][3];
        if (j == heads[b * SS + i])
            ce[b * SS + i] = (i >= 1) ? (__logf(tot) - sv_[ii]) : 0.f;
    }

    // ---- fused loss finisher ----
    __threadfence();                 // publish ce (device scope)
    __syncthreads();
    if (j == 0) {
        int vdone = atomicAdd(cnt, 1);
        lastFlag = (vdone == (int)gridDim.x - 1);
    }
    __syncthreads();
    if (lastFlag) {
        __threadfence();             // acquire: all ce stores visible
        __shared__ float red[256];
        float a = 0.f;
        for (int k = j; k < BB * SS; k += 256) a += ce[k];
        red[j] = a; __syncthreads();
        for (int off = 128; off > 0; off >>= 1) {
            if (j < off) red[j] += red[j + off];
            __syncthreads();
        }
        if (j == 0) out[0] = red[0] * (1.f / BB);
    }
}

extern "C" void kernel_launch(void* const* d_in, const int* in_sizes, int n_in,
                              void* d_out, int out_size, void* d_ws, size_t ws_size,
                              hipStream_t stream)
{
    const int*   words = (const int*)  d_in[0];
    const int*   pos   = (const int*)  d_in[1];
    const float* morph = (const float*)d_in[2];
    const int*   heads = (const int*)  d_in[3];
    const float* wtab  = (const float*)d_in[4];
    const float* ptab  = (const float*)d_in[5];
    const float* Wxf   = (const float*)d_in[6];
    const float* Whf   = (const float*)d_in[7];
    const float* bf    = (const float*)d_in[8];
    const float* Wxb   = (const float*)d_in[9];
    const float* Whb   = (const float*)d_in[10];
    const float* bb    = (const float*)d_in[11];
    const float* Wu    = (const float*)d_in[12];
    const float* bu    = (const float*)d_in[13];
    const float* Ww    = (const float*)d_in[14];
    const float* bw    = (const float*)d_in[15];
    const float* v     = (const float*)d_in[16];
    float* out = (float*)d_out;

    // workspace layout (floats)
    float* xgf  = (float*)d_ws;                  // 8192*24 (prescaled)
    float* xgb  = xgf  + (size_t)BB*SS*G4;       // 8192*24 (prescaled)
    float* ua   = xgb  + (size_t)BB*SS*G4;       // 8192*12 (prescaled 2log2e)
    float* wa   = ua   + (size_t)BB*SS*AA;       // 8192*12 (prescaled 2log2e)
    float* ce   = wa   + (size_t)BB*SS*AA;       // 8192
    int*   cnt  = (int*)(ce + (size_t)BB*SS);    // 1 (zeroed by k_lstm_uawa)

    k_embed_proj<<<(BB * SS) / EPB, 256, 0, stream>>>(words, pos, morph, wtab, ptab,
                                                      Wxf, bf, Wxb, bb, xgf, xgb);
    k_lstm_uawa<<<BB, 128, 0, stream>>>(xgf, xgb, Whf, Whb, Wu, bu, Ww, bw, ua, wa, cnt);
    k_score<<<BB * (SS / 4), 256, 0, stream>>>(ua, wa, v, heads, out, ce, cnt);
}

// Round 17
// 70.954 us; speedup vs baseline: 3.1795x; 3.1795x over previous
//
#include <hip/hip_runtime.h>
#include <hip/hip_bf16.h>

// Problem constants
#define BB 32
#define SS 256
#define DD 300
#define PDD 32
#define MM 66
#define FF 398      // D + PD + M
#define HH 6
#define G4 24       // 4*H
#define AA 12
#define L2E 1.4426950408889634f

__device__ __forceinline__ float fast_rcp(float x) { return __builtin_amdgcn_rcpf(x); }
__device__ __forceinline__ float bcast_lane(float x, int l) {
    return __int_as_float(__builtin_amdgcn_readlane(__float_as_int(x), l));
}
template<int CTRL>
__device__ __forceinline__ float quad_bcast(float v) {
    return __int_as_float(__builtin_amdgcn_mov_dpp(__float_as_int(v), CTRL, 0xf, 0xf, true));
}

// -------------------------------------------------------------------------
// Kernel 1 (v7, kept from R16): fused embed+concat+projection, all-LDS,
// 2-pos register tile. Per q: 2 feat b128 + 3 W b128 for 24 fma.
// sW rows padded to 101 float4 -> 2-way bank access (free).
// Epilogue folds bias + the lstm's +-log2e gate prescale.
// -------------------------------------------------------------------------
#define EPB 32
__global__ __launch_bounds__(256) void k_embed_proj(
    const int* __restrict__ words, const int* __restrict__ pos,
    const float* __restrict__ morph, const float* __restrict__ wtab,
    const float* __restrict__ ptab,
    const float* __restrict__ Wxf, const float* __restrict__ bfv,
    const float* __restrict__ Wxb, const float* __restrict__ bbv,
    float* __restrict__ xgf, float* __restrict__ xgb)
{
    __shared__ float4 sF[100][33];      // 52.8 KB
    __shared__ float4 sW[48 * 101];     // 77.6 KB (row stride 101 float4)
    int t  = threadIdx.x;
    int p0 = blockIdx.x * EPB;

    for (int idx = t; idx < EPB * 75; idx += 256) {
        int p = idx / 75, q = idx % 75;
        sF[q][p] = *(const float4*)(wtab + (size_t)words[p0 + p] * DD + 4 * q);
    }
    {
        int idx = t;                    // EPB*8 = 256 exactly
        int p = idx / 8, q = idx % 8;
        sF[75 + q][p] = *(const float4*)(ptab + pos[p0 + p] * PDD + 4 * q);
    }
    for (int idx = t; idx < EPB * 17; idx += 256) {
        int p = idx / 17, mq = idx % 17;
        const float2* ms = (const float2*)(morph + (size_t)(p0 + p) * MM);
        float2 lo = ms[2 * mq];
        float2 hi = (mq < 16) ? ms[2 * mq + 1] : make_float2(0.f, 0.f);
        sF[83 + mq][p] = make_float4(lo.x, lo.y, hi.x, hi.y);
    }
    {
        float* sWf = (float*)sW;
        for (int idx = t; idx < FF * G4; idx += 256) {
            int k = idx / G4, j = idx % G4;
            sWf[j * 404 + k]        = Wxf[idx];
            sWf[(24 + j) * 404 + k] = Wxb[idx];
        }
        if (t < 2 * G4) {               // zero pad k = 398,399
            int j = t >> 1, k = 398 + (t & 1);
            sWf[j * 404 + k] = 0.f; sWf[(24 + j) * 404 + k] = 0.f;
        }
    }
    __syncthreads();

    int cg = t & 15;                    // 3-col group: cols 3cg..3cg+2 (0..47)
    int pp = t >> 4;                    // positions pp and pp+16
    int c0 = 3 * cg;                    // group never straddles the 24 boundary
    int dir = c0 >= 24 ? 1 : 0;
    int jj  = c0 - dir * 24;
    const float4* W0 = sW + (size_t)(dir * 24 + jj + 0) * 101;
    const float4* W1 = sW + (size_t)(dir * 24 + jj + 1) * 101;
    const float4* W2 = sW + (size_t)(dir * 24 + jj + 2) * 101;

    float a00 = 0.f, a01 = 0.f, a02 = 0.f;
    float a10 = 0.f, a11 = 0.f, a12 = 0.f;
    #pragma unroll 4
    for (int q = 0; q < 100; ++q) {
        float4 f0 = sF[q][pp];
        float4 f1 = sF[q][pp + 16];
        float4 w0 = W0[q], w1 = W1[q], w2 = W2[q];
        a00 = fmaf(f0.x, w0.x, a00); a00 = fmaf(f0.y, w0.y, a00);
        a00 = fmaf(f0.z, w0.z, a00); a00 = fmaf(f0.w, w0.w, a00);
        a01 = fmaf(f0.x, w1.x, a01); a01 = fmaf(f0.y, w1.y, a01);
        a01 = fmaf(f0.z, w1.z, a01); a01 = fmaf(f0.w, w1.w, a01);
        a02 = fmaf(f0.x, w2.x, a02); a02 = fmaf(f0.y, w2.y, a02);
        a02 = fmaf(f0.z, w2.z, a02); a02 = fmaf(f0.w, w2.w, a02);
        a10 = fmaf(f1.x, w0.x, a10); a10 = fmaf(f1.y, w0.y, a10);
        a10 = fmaf(f1.z, w0.z, a10); a10 = fmaf(f1.w, w0.w, a10);
        a11 = fmaf(f1.x, w1.x, a11); a11 = fmaf(f1.y, w1.y, a11);
        a11 = fmaf(f1.z, w1.z, a11); a11 = fmaf(f1.w, w1.w, a11);
        a12 = fmaf(f1.x, w2.x, a12); a12 = fmaf(f1.y, w2.y, a12);
        a12 = fmaf(f1.z, w2.z, a12); a12 = fmaf(f1.w, w2.w, a12);
    }

    float kk = (jj >= 12 && jj < 18) ? 2.f * L2E : -L2E;
    const float* bias = dir ? bbv : bfv;
    float b0 = bias[jj], b1 = bias[jj + 1], b2 = bias[jj + 2];
    float* xg = dir ? xgb : xgf;
    float* o0 = xg + (size_t)(p0 + pp) * G4 + jj;
    float* o1 = xg + (size_t)(p0 + pp + 16) * G4 + jj;
    o0[0] = (a00 + b0) * kk; o0[1] = (a01 + b1) * kk; o0[2] = (a02 + b2) * kk;
    o1[0] = (a10 + b0) * kk; o1[1] = (a11 + b1) * kk; o1[2] = (a12 + b2) * kk;
}

// -------------------------------------------------------------------------
// Kernel 2 (R15-verbatim): LSTM + uawa fused. Block = one batch, 2 waves =
// fwd/bwd chains on separate SIMDs. Epilogue: ua/wa PRESCALED by 2*log2e.
// -------------------------------------------------------------------------
__global__ __launch_bounds__(128) void k_lstm_uawa(
    const float* __restrict__ xgf, const float* __restrict__ xgb,
    const float* __restrict__ Whf, const float* __restrict__ Whb,
    const float* __restrict__ Wu, const float* __restrict__ bu,
    const float* __restrict__ Ww, const float* __restrict__ bw,
    float* __restrict__ ua, float* __restrict__ wa)
{
    __shared__ float sxg[2][(SS + 8) * G4];   // 50.7 KB
    __shared__ float hbuf[2][SS * HH];        // 12 KB
    int b    = blockIdx.x;                    // 0..31
    int lane = threadIdx.x & 63;
    int dir  = __builtin_amdgcn_readfirstlane(threadIdx.x >> 6);

    const float* xg = (dir ? xgb : xgf) + (size_t)b * SS * G4;
    const float* Wh = dir ? Whb : Whf;

    {
        const float4* src = (const float4*)xg;
        float4* dst = (float4*)sxg[dir];
        #pragma unroll
        for (int u = 0; u < 24; ++u) {
            int d = lane + u * 64;            // float4 index 0..1535
            int row = d / 6, c4 = d - row * 6;
            int drow = dir ? (SS - 1 - row) : row;
            dst[drow * 6 + c4] = src[d];
        }
        for (int g2 = lane; g2 < 8 * G4; g2 += 64) sxg[dir][SS * G4 + g2] = 0.f;
    }

    int g    = lane % G4;                   // gate slot 0..23
    int cell = g >> 2;                      // 0..5
    int type = g & 3;                       // 0=i 1=f 2=c 3=o
    int j    = type * HH + cell;            // keras column

    float kk = (type == 2) ? 2.f * L2E : -L2E;
    float wh[HH];
    #pragma unroll
    for (int m = 0; m < HH; ++m) wh[m] = Wh[m * G4 + j] * kk;
    float Bc = (type == 2) ? 1.f : 0.f;
    float Ac = (type == 2) ? -1.f : 1.f;

    float sh[HH];
    #pragma unroll
    for (int m = 0; m < HH; ++m) sh[m] = 0.f;
    float c = 0.f;
    bool wr = (lane < G4) && ((lane & 3) == 0);

    const float* xb = sxg[dir] + j;
    float* hb = hbuf[dir];

    float pg[4];
    #pragma unroll
    for (int sl = 0; sl < 4; ++sl) pg[sl] = xb[sl * G4];

    #pragma unroll 1
    for (int t = 0; t < SS; t += 4) {
        #pragma unroll
        for (int sl = 0; sl < 4; ++sl) {
            float x = pg[sl];
            pg[sl] = xb[(t + 4 + sl) * G4];      // guard rows cover the tail

            float aa  = fmaf(sh[1], wh[1], fmaf(sh[0], wh[0], x));
            float bb2 = fmaf(sh[3], wh[3], sh[2] * wh[2]);
            float cc2 = fmaf(sh[5], wh[5], sh[4] * wh[4]);
            x = (aa + bb2) + cc2;

            float e   = __builtin_amdgcn_exp2f(x);
            float val = fmaf(Bc, e, Ac) * fast_rcp(1.f + e);

            float vi = quad_bcast<0>(val);
            float vf = quad_bcast<85>(val);
            float vc = quad_bcast<170>(val);
            float vo = quad_bcast<255>(val);

            c = fmaf(vf, c, vi * vc);
            float ec = __builtin_amdgcn_exp2f(c * (2.f * L2E));
            float h  = (ec - 1.f) * fast_rcp(ec + 1.f) * vo;

            if (wr) hb[(t + sl) * HH + cell] = h;
            #pragma unroll
            for (int m = 0; m < HH; ++m) sh[m] = bcast_lane(h, 4 * m);
        }
    }
    __syncthreads();

    // epilogue: ua/wa (prescaled 2*log2e) for this batch's 256 positions.
    #pragma unroll
    for (int half = 0; half < 2; ++half) {
        int s = (int)threadIdx.x + half * 128;
        float r[AA];
        #pragma unroll
        for (int cc = 0; cc < HH; ++cc) {
            r[cc]      = hbuf[0][s * HH + cc];
            r[HH + cc] = hbuf[1][(SS - 1 - s) * HH + cc];
        }
        float au[AA], aw[AA];
        #pragma unroll
        for (int d = 0; d < AA; ++d) { au[d] = bu[d]; aw[d] = bw[d]; }
        #pragma unroll
        for (int e2 = 0; e2 < AA; ++e2) {
            #pragma unroll
            for (int d = 0; d < AA; ++d) {
                au[d] = fmaf(r[e2], Wu[e2 * AA + d], au[d]);
                aw[d] = fmaf(r[e2], Ww[e2 * AA + d], aw[d]);
            }
        }
        float* ou = ua + ((size_t)b * SS + s) * AA;
        float* ow = wa + ((size_t)b * SS + s) * AA;
        #pragma unroll
        for (int d4 = 0; d4 < 3; ++d4) {
            *(float4*)(ou + 4 * d4) = make_float4(au[4*d4] * (2.f*L2E), au[4*d4+1] * (2.f*L2E),
                                                  au[4*d4+2] * (2.f*L2E), au[4*d4+3] * (2.f*L2E));
            *(float4*)(ow + 4 * d4) = make_float4(aw[4*d4] * (2.f*L2E), aw[4*d4+1] * (2.f*L2E),
                                                  aw[4*d4+2] * (2.f*L2E), aw[4*d4+3] * (2.f*L2E));
        }
    }
}

// -------------------------------------------------------------------------
// Kernel 4 (v3, R15-verbatim — NO fused finisher; R16 lesson: device-scope
// threadfence x2048 blocks serializes cross-XCD -> 181 µs): arc scores,
// 4 dependants per block (grid 2048), ua row loaded once, exp2 tanh.
// -------------------------------------------------------------------------
__global__ __launch_bounds__(256) void k_score(
    const float* __restrict__ ua, const float* __restrict__ wa,
    const float* __restrict__ v, const int* __restrict__ heads,
    float* __restrict__ out, float* __restrict__ ce)
{
    int blk = blockIdx.x;           // b*64 + ig
    int b   = blk >> 6;
    int i0  = (blk & 63) * 4;
    int j   = threadIdx.x;
    int w   = j >> 6;

    __shared__ float swa[4][AA], sv[AA];
    __shared__ float part[4][4];
    if (j < 4 * AA) swa[j / AA][j % AA] = wa[((size_t)b * SS + i0 + j / AA) * AA + j % AA];
    if (j < AA) sv[j] = v[j];
    __syncthreads();

    float sumv = 0.f;
    #pragma unroll
    for (int d = 0; d < AA; ++d) sumv += sv[d];

    const float* uj = ua + ((size_t)b * SS + j) * AA;
    float4 u0 = *(const float4*)(uj);
    float4 u1 = *(const float4*)(uj + 4);
    float4 u2 = *(const float4*)(uj + 8);
    float us[AA] = {u0.x, u0.y, u0.z, u0.w, u1.x, u1.y, u1.z, u1.w,
                    u2.x, u2.y, u2.z, u2.w};

    float sv_[4];
    #pragma unroll
    for (int ii = 0; ii < 4; ++ii) {
        int i = i0 + ii;
        float acc = 0.f;
        #pragma unroll
        for (int d = 0; d < AA; ++d) {
            float e_d = __builtin_amdgcn_exp2f(us[d] + swa[ii][d]);
            acc = fmaf(sv[d], fast_rcp(1.f + e_d), acc);
        }
        float s = fmaf(-2.f, acc, sumv);
        if (j == i) s = -10000.f;
        sv_[ii] = s;

        float e = __builtin_amdgcn_exp2f(s * L2E);
        if (i >= 1)
            out[1 + (((size_t)(i - 1) * BB + b) * SS + j)] = e;

        float r = e;
        #pragma unroll
        for (int off = 32; off > 0; off >>= 1) r += __shfl_xor(r, off, 64);
        if ((j & 63) == 0) part[ii][w] = r;
    }
    __syncthreads();

    #pragma unroll
    for (int ii = 0; ii < 4; ++ii) {
        int i = i0 + ii;
        float tot = part[ii][0] + part[ii][1] + part[ii][2] + part[ii][3];
        if (j == heads[b * SS + i])
            ce[b * SS + i] = (i >= 1) ? (__logf(tot) - sv_[ii]) : 0.f;
    }
}

// -------------------------------------------------------------------------
// Kernel 5: deterministic loss reduction: sum(ce)/B into out[0].
// -------------------------------------------------------------------------
__global__ __launch_bounds__(256) void k_loss(const float* __restrict__ ce,
                                              float* __restrict__ out)
{
    __shared__ float red[256];
    int t = threadIdx.x;
    float a = 0.f;
    for (int k = t; k < BB * SS; k += 256) a += ce[k];
    red[t] = a; __syncthreads();
    for (int off = 128; off > 0; off >>= 1) {
        if (t < off) red[t] += red[t + off];
        __syncthreads();
    }
    if (t == 0) out[0] = red[0] * (1.f / BB);
}

extern "C" void kernel_launch(void* const* d_in, const int* in_sizes, int n_in,
                              void* d_out, int out_size, void* d_ws, size_t ws_size,
                              hipStream_t stream)
{
    const int*   words = (const int*)  d_in[0];
    const int*   pos   = (const int*)  d_in[1];
    const float* morph = (const float*)d_in[2];
    const int*   heads = (const int*)  d_in[3];
    const float* wtab  = (const float*)d_in[4];
    const float* ptab  = (const float*)d_in[5];
    const float* Wxf   = (const float*)d_in[6];
    const float* Whf   = (const float*)d_in[7];
    const float* bf    = (const float*)d_in[8];
    const float* Wxb   = (const float*)d_in[9];
    const float* Whb   = (const float*)d_in[10];
    const float* bb    = (const float*)d_in[11];
    const float* Wu    = (const float*)d_in[12];
    const float* bu    = (const float*)d_in[13];
    const float* Ww    = (const float*)d_in[14];
    const float* bw    = (const float*)d_in[15];
    const float* v     = (const float*)d_in[16];
    float* out = (float*)d_out;

    // workspace layout (floats)
    float* xgf  = (float*)d_ws;                  // 8192*24 (prescaled)
    float* xgb  = xgf  + (size_t)BB*SS*G4;       // 8192*24 (prescaled)
    float* ua   = xgb  + (size_t)BB*SS*G4;       // 8192*12 (prescaled 2log2e)
    float* wa   = ua   + (size_t)BB*SS*AA;       // 8192*12 (prescaled 2log2e)
    float* ce   = wa   + (size_t)BB*SS*AA;       // 8192

    k_embed_proj<<<(BB * SS) / EPB, 256, 0, stream>>>(words, pos, morph, wtab, ptab,
                                                      Wxf, bf, Wxb, bb, xgf, xgb);
    k_lstm_uawa<<<BB, 128, 0, stream>>>(xgf, xgb, Whf, Whb, Wu, bu, Ww, bw, ua, wa);
    k_score<<<BB * (SS / 4), 256, 0, stream>>>(ua, wa, v, heads, out, ce);
    k_loss<<<1, 256, 0, stream>>>(ce, out);
}

// Round 18
// 69.643 us; speedup vs baseline: 3.2393x; 1.0188x over previous
//
#include <hip/hip_runtime.h>
#include <hip/hip_bf16.h>

// Problem constants
#define BB 32
#define SS 256
#define DD 300
#define PDD 32
#define MM 66
#define FF 398      // D + PD + M
#define HH 6
#define G4 24       // 4*H
#define AA 12
#define L2E 1.4426950408889634f

__device__ __forceinline__ float fast_rcp(float x) { return __builtin_amdgcn_rcpf(x); }
__device__ __forceinline__ float bcast_lane(float x, int l) {
    return __int_as_float(__builtin_amdgcn_readlane(__float_as_int(x), l));
}
template<int CTRL>
__device__ __forceinline__ float quad_bcast(float v) {
    return __int_as_float(__builtin_amdgcn_mov_dpp(__float_as_int(v), CTRL, 0xf, 0xf, true));
}

// -------------------------------------------------------------------------
// Kernel 1 (v7 + XCD-aligned mapping): fused embed+concat+projection.
// Block e -> batch e%32, chunk e/32: all 8 blocks producing batch b's xg
// run on XCD b%8 — the same XCD where lstm block b will read it (L2-local
// handoff). Per q: 2 feat b128 + 3 W b128 for 24 fma; sW rows padded to
// 101 float4 (2-way bank access, free). Epilogue folds bias + prescale.
// -------------------------------------------------------------------------
#define EPB 32
__global__ __launch_bounds__(256) void k_embed_proj(
    const int* __restrict__ words, const int* __restrict__ pos,
    const float* __restrict__ morph, const float* __restrict__ wtab,
    const float* __restrict__ ptab,
    const float* __restrict__ Wxf, const float* __restrict__ bfv,
    const float* __restrict__ Wxb, const float* __restrict__ bbv,
    float* __restrict__ xgf, float* __restrict__ xgb)
{
    __shared__ float4 sF[100][33];      // 52.8 KB
    __shared__ float4 sW[48 * 101];     // 77.6 KB (row stride 101 float4)
    int t  = threadIdx.x;
    int e  = blockIdx.x;
    int p0 = (e & 31) * SS + (e >> 5) * EPB;   // batch e%32, chunk e/32

    for (int idx = t; idx < EPB * 75; idx += 256) {
        int p = idx / 75, q = idx % 75;
        sF[q][p] = *(const float4*)(wtab + (size_t)words[p0 + p] * DD + 4 * q);
    }
    {
        int idx = t;                    // EPB*8 = 256 exactly
        int p = idx / 8, q = idx % 8;
        sF[75 + q][p] = *(const float4*)(ptab + pos[p0 + p] * PDD + 4 * q);
    }
    for (int idx = t; idx < EPB * 17; idx += 256) {
        int p = idx / 17, mq = idx % 17;
        const float2* ms = (const float2*)(morph + (size_t)(p0 + p) * MM);
        float2 lo = ms[2 * mq];
        float2 hi = (mq < 16) ? ms[2 * mq + 1] : make_float2(0.f, 0.f);
        sF[83 + mq][p] = make_float4(lo.x, lo.y, hi.x, hi.y);
    }
    {
        float* sWf = (float*)sW;
        for (int idx = t; idx < FF * G4; idx += 256) {
            int k = idx / G4, j = idx % G4;
            sWf[j * 404 + k]        = Wxf[idx];
            sWf[(24 + j) * 404 + k] = Wxb[idx];
        }
        if (t < 2 * G4) {               // zero pad k = 398,399
            int j = t >> 1, k = 398 + (t & 1);
            sWf[j * 404 + k] = 0.f; sWf[(24 + j) * 404 + k] = 0.f;
        }
    }
    __syncthreads();

    int cg = t & 15;                    // 3-col group: cols 3cg..3cg+2 (0..47)
    int pp = t >> 4;                    // positions pp and pp+16
    int c0 = 3 * cg;                    // group never straddles the 24 boundary
    int dir = c0 >= 24 ? 1 : 0;
    int jj  = c0 - dir * 24;
    const float4* W0 = sW + (size_t)(dir * 24 + jj + 0) * 101;
    const float4* W1 = sW + (size_t)(dir * 24 + jj + 1) * 101;
    const float4* W2 = sW + (size_t)(dir * 24 + jj + 2) * 101;

    float a00 = 0.f, a01 = 0.f, a02 = 0.f;
    float a10 = 0.f, a11 = 0.f, a12 = 0.f;
    #pragma unroll 4
    for (int q = 0; q < 100; ++q) {
        float4 f0 = sF[q][pp];
        float4 f1 = sF[q][pp + 16];
        float4 w0 = W0[q], w1 = W1[q], w2 = W2[q];
        a00 = fmaf(f0.x, w0.x, a00); a00 = fmaf(f0.y, w0.y, a00);
        a00 = fmaf(f0.z, w0.z, a00); a00 = fmaf(f0.w, w0.w, a00);
        a01 = fmaf(f0.x, w1.x, a01); a01 = fmaf(f0.y, w1.y, a01);
        a01 = fmaf(f0.z, w1.z, a01); a01 = fmaf(f0.w, w1.w, a01);
        a02 = fmaf(f0.x, w2.x, a02); a02 = fmaf(f0.y, w2.y, a02);
        a02 = fmaf(f0.z, w2.z, a02); a02 = fmaf(f0.w, w2.w, a02);
        a10 = fmaf(f1.x, w0.x, a10); a10 = fmaf(f1.y, w0.y, a10);
        a10 = fmaf(f1.z, w0.z, a10); a10 = fmaf(f1.w, w0.w, a10);
        a11 = fmaf(f1.x, w1.x, a11); a11 = fmaf(f1.y, w1.y, a11);
        a11 = fmaf(f1.z, w1.z, a11); a11 = fmaf(f1.w, w1.w, a11);
        a12 = fmaf(f1.x, w2.x, a12); a12 = fmaf(f1.y, w2.y, a12);
        a12 = fmaf(f1.z, w2.z, a12); a12 = fmaf(f1.w, w2.w, a12);
    }

    float kk = (jj >= 12 && jj < 18) ? 2.f * L2E : -L2E;
    const float* bias = dir ? bbv : bfv;
    float b0 = bias[jj], b1 = bias[jj + 1], b2 = bias[jj + 2];
    float* xg = dir ? xgb : xgf;
    float* o0 = xg + (size_t)(p0 + pp) * G4 + jj;
    float* o1 = xg + (size_t)(p0 + pp + 16) * G4 + jj;
    o0[0] = (a00 + b0) * kk; o0[1] = (a01 + b1) * kk; o0[2] = (a02 + b2) * kk;
    o1[0] = (a10 + b0) * kk; o1[1] = (a11 + b1) * kk; o1[2] = (a12 + b2) * kk;
}

// -------------------------------------------------------------------------
// Kernel 2 (v13): LSTM + uawa fused; 3 serial ops removed per step:
// (a) tanh-lane outputs val = 2L2E*tanh (Bc2=-4L2E, Ac2=2L2E) so the cell
//     accumulator ct lives in 2L2E-scaled units -> no pre-exp2 multiply;
// (b) h = vo - 2vo*rcp(ec+1) (fma; two_vo computed off-path) replaces
//     (ec-1)*rcp*mul;
// (c) val itself is a single fma of rcp (sigmoid: r; tanh: 2L2E(1-2r)).
// Chain/step: dot(4) -> exp2 -> add -> rcp -> fma -> dpp -> mul -> fma ->
// exp2 -> add -> rcp -> fma -> readlane.
// -------------------------------------------------------------------------
__global__ __launch_bounds__(128) void k_lstm_uawa(
    const float* __restrict__ xgf, const float* __restrict__ xgb,
    const float* __restrict__ Whf, const float* __restrict__ Whb,
    const float* __restrict__ Wu, const float* __restrict__ bu,
    const float* __restrict__ Ww, const float* __restrict__ bw,
    float* __restrict__ ua, float* __restrict__ wa)
{
    __shared__ float sxg[2][(SS + 8) * G4];   // 50.7 KB
    __shared__ float hbuf[2][SS * HH];        // 12 KB
    int b    = blockIdx.x;                    // 0..31
    int lane = threadIdx.x & 63;
    int dir  = __builtin_amdgcn_readfirstlane(threadIdx.x >> 6);

    const float* xg = (dir ? xgb : xgf) + (size_t)b * SS * G4;
    const float* Wh = dir ? Whb : Whf;

    {
        const float4* src = (const float4*)xg;
        float4* dst = (float4*)sxg[dir];
        #pragma unroll
        for (int u = 0; u < 24; ++u) {
            int d = lane + u * 64;            // float4 index 0..1535
            int row = d / 6, c4 = d - row * 6;
            int drow = dir ? (SS - 1 - row) : row;
            dst[drow * 6 + c4] = src[d];
        }
        for (int g2 = lane; g2 < 8 * G4; g2 += 64) sxg[dir][SS * G4 + g2] = 0.f;
    }

    int g    = lane % G4;                   // gate slot 0..23
    int cell = g >> 2;                      // 0..5
    int type = g & 3;                       // 0=i 1=f 2=c 3=o
    int j    = type * HH + cell;            // keras column

    float kk = (type == 2) ? 2.f * L2E : -L2E;
    float wh[HH];
    #pragma unroll
    for (int m = 0; m < HH; ++m) wh[m] = Wh[m * G4 + j] * kk;
    // val = fma(Bc2, r, Ac2), r = rcp(1+exp2(xhat)):
    //   sigmoid lanes: r ;  tanh lane: 2L2E*(1-2r) = 2L2E*tanh
    float Bc2 = (type == 2) ? -4.f * L2E : 1.f;
    float Ac2 = (type == 2) ?  2.f * L2E : 0.f;

    float sh[HH];
    #pragma unroll
    for (int m = 0; m < HH; ++m) sh[m] = 0.f;
    float ct = 0.f;                         // cell in 2L2E-scaled units
    bool wr = (lane < G4) && ((lane & 3) == 0);

    const float* xb = sxg[dir] + j;
    float* hb = hbuf[dir];

    float pg[4];
    #pragma unroll
    for (int sl = 0; sl < 4; ++sl) pg[sl] = xb[sl * G4];

    #pragma unroll 1
    for (int t = 0; t < SS; t += 4) {
        #pragma unroll
        for (int sl = 0; sl < 4; ++sl) {
            float x = pg[sl];
            pg[sl] = xb[(t + 4 + sl) * G4];      // guard rows cover the tail

            float aa  = fmaf(sh[1], wh[1], fmaf(sh[0], wh[0], x));
            float bb2 = fmaf(sh[3], wh[3], sh[2] * wh[2]);
            float cc2 = fmaf(sh[5], wh[5], sh[4] * wh[4]);
            x = (aa + bb2) + cc2;

            float e   = __builtin_amdgcn_exp2f(x);
            float r   = fast_rcp(1.f + e);
            float val = fmaf(Bc2, r, Ac2);

            float vi = quad_bcast<0>(val);
            float vf = quad_bcast<85>(val);
            float vc = quad_bcast<170>(val);     // carries 2L2E scale
            float vo = quad_bcast<255>(val);

            float prod   = vi * vc;
            float two_vo = vo + vo;              // off the serial path
            ct = fmaf(vf, ct, prod);             // ct = 2L2E * c
            float ec = __builtin_amdgcn_exp2f(ct);   // = e^{2c}
            float r2 = fast_rcp(ec + 1.f);
            float h  = fmaf(-two_vo, r2, vo);    // vo * tanh(c)

            if (wr) hb[(t + sl) * HH + cell] = h;
            #pragma unroll
            for (int m = 0; m < HH; ++m) sh[m] = bcast_lane(h, 4 * m);
        }
    }
    __syncthreads();

    // epilogue: ua/wa (prescaled 2*log2e) for this batch's 256 positions.
    #pragma unroll
    for (int half = 0; half < 2; ++half) {
        int s = (int)threadIdx.x + half * 128;
        float r[AA];
        #pragma unroll
        for (int cc = 0; cc < HH; ++cc) {
            r[cc]      = hbuf[0][s * HH + cc];
            r[HH + cc] = hbuf[1][(SS - 1 - s) * HH + cc];
        }
        float au[AA], aw[AA];
        #pragma unroll
        for (int d = 0; d < AA; ++d) { au[d] = bu[d]; aw[d] = bw[d]; }
        #pragma unroll
        for (int e2 = 0; e2 < AA; ++e2) {
            #pragma unroll
            for (int d = 0; d < AA; ++d) {
                au[d] = fmaf(r[e2], Wu[e2 * AA + d], au[d]);
                aw[d] = fmaf(r[e2], Ww[e2 * AA + d], aw[d]);
            }
        }
        float* ou = ua + ((size_t)b * SS + s) * AA;
        float* ow = wa + ((size_t)b * SS + s) * AA;
        #pragma unroll
        for (int d4 = 0; d4 < 3; ++d4) {
            *(float4*)(ou + 4 * d4) = make_float4(au[4*d4] * (2.f*L2E), au[4*d4+1] * (2.f*L2E),
                                                  au[4*d4+2] * (2.f*L2E), au[4*d4+3] * (2.f*L2E));
            *(float4*)(ow + 4 * d4) = make_float4(aw[4*d4] * (2.f*L2E), aw[4*d4+1] * (2.f*L2E),
                                                  aw[4*d4+2] * (2.f*L2E), aw[4*d4+3] * (2.f*L2E));
        }
    }
}

// -------------------------------------------------------------------------
// Kernel 4 (v3, unchanged): arc scores, 4 dependants per block (grid 2048),
// ua row loaded once, exp2 tanh on prescaled inputs. No fences/atomics
// (R16 lesson: cross-XCD threadfence x2048 blocks = 181 µs).
// -------------------------------------------------------------------------
__global__ __launch_bounds__(256) void k_score(
    const float* __restrict__ ua, const float* __restrict__ wa,
    const float* __restrict__ v, const int* __restrict__ heads,
    float* __restrict__ out, float* __restrict__ ce)
{
    int blk = blockIdx.x;           // b*64 + ig
    int b   = blk >> 6;
    int i0  = (blk & 63) * 4;
    int j   = threadIdx.x;
    int w   = j >> 6;

    __shared__ float swa[4][AA], sv[AA];
    __shared__ float part[4][4];
    if (j < 4 * AA) swa[j / AA][j % AA] = wa[((size_t)b * SS + i0 + j / AA) * AA + j % AA];
    if (j < AA) sv[j] = v[j];
    __syncthreads();

    float sumv = 0.f;
    #pragma unroll
    for (int d = 0; d < AA; ++d) sumv += sv[d];

    const float* uj = ua + ((size_t)b * SS + j) * AA;
    float4 u0 = *(const float4*)(uj);
    float4 u1 = *(const float4*)(uj + 4);
    float4 u2 = *(const float4*)(uj + 8);
    float us[AA] = {u0.x, u0.y, u0.z, u0.w, u1.x, u1.y, u1.z, u1.w,
                    u2.x, u2.y, u2.z, u2.w};

    float sv_[4];
    #pragma unroll
    for (int ii = 0; ii < 4; ++ii) {
        int i = i0 + ii;
        float acc = 0.f;
        #pragma unroll
        for (int d = 0; d < AA; ++d) {
            float e_d = __builtin_amdgcn_exp2f(us[d] + swa[ii][d]);
            acc = fmaf(sv[d], fast_rcp(1.f + e_d), acc);
        }
        float s = fmaf(-2.f, acc, sumv);
        if (j == i) s = -10000.f;
        sv_[ii] = s;

        float e = __builtin_amdgcn_exp2f(s * L2E);
        if (i >= 1)
            out[1 + (((size_t)(i - 1) * BB + b) * SS + j)] = e;

        float r = e;
        #pragma unroll
        for (int off = 32; off > 0; off >>= 1) r += __shfl_xor(r, off, 64);
        if ((j & 63) == 0) part[ii][w] = r;
    }
    __syncthreads();

    #pragma unroll
    for (int ii = 0; ii < 4; ++ii) {
        int i = i0 + ii;
        float tot = part[ii][0] + part[ii][1] + part[ii][2] + part[ii][3];
        if (j == heads[b * SS + i])
            ce[b * SS + i] = (i >= 1) ? (__logf(tot) - sv_[ii]) : 0.f;
    }
}

// -------------------------------------------------------------------------
// Kernel 5: deterministic loss reduction: sum(ce)/B into out[0].
// -------------------------------------------------------------------------
__global__ __launch_bounds__(256) void k_loss(const float* __restrict__ ce,
                                              float* __restrict__ out)
{
    __shared__ float red[256];
    int t = threadIdx.x;
    float a = 0.f;
    for (int k = t; k < BB * SS; k += 256) a += ce[k];
    red[t] = a; __syncthreads();
    for (int off = 128; off > 0; off >>= 1) {
        if (t < off) red[t] += red[t + off];
        __syncthreads();
    }
    if (t == 0) out[0] = red[0] * (1.f / BB);
}

extern "C" void kernel_launch(void* const* d_in, const int* in_sizes, int n_in,
                              void* d_out, int out_size, void* d_ws, size_t ws_size,
                              hipStream_t stream)
{
    const int*   words = (const int*)  d_in[0];
    const int*   pos   = (const int*)  d_in[1];
    const float* morph = (const float*)d_in[2];
    const int*   heads = (const int*)  d_in[3];
    const float* wtab  = (const float*)d_in[4];
    const float* ptab  = (const float*)d_in[5];
    const float* Wxf   = (const float*)d_in[6];
    const float* Whf   = (const float*)d_in[7];
    const float* bf    = (const float*)d_in[8];
    const float* Wxb   = (const float*)d_in[9];
    const float* Whb   = (const float*)d_in[10];
    const float* bb    = (const float*)d_in[11];
    const float* Wu    = (const float*)d_in[12];
    const float* bu    = (const float*)d_in[13];
    const float* Ww    = (const float*)d_in[14];
    const float* bw    = (const float*)d_in[15];
    const float* v     = (const float*)d_in[16];
    float* out = (float*)d_out;

    // workspace layout (floats)
    float* xgf  = (float*)d_ws;                  // 8192*24 (prescaled)
    float* xgb  = xgf  + (size_t)BB*SS*G4;       // 8192*24 (prescaled)
    float* ua   = xgb  + (size_t)BB*SS*G4;       // 8192*12 (prescaled 2log2e)
    float* wa   = ua   + (size_t)BB*SS*AA;       // 8192*12 (prescaled 2log2e)
    float* ce   = wa   + (size_t)BB*SS*AA;       // 8192

    k_embed_proj<<<(BB * SS) / EPB, 256, 0, stream>>>(words, pos, morph, wtab, ptab,
                                                      Wxf, bf, Wxb, bb, xgf, xgb);
    k_lstm_uawa<<<BB, 128, 0, stream>>>(xgf, xgb, Whf, Whb, Wu, bu, Ww, bw, ua, wa);
    k_score<<<BB * (SS / 4), 256, 0, stream>>>(ua, wa, v, heads, out, ce);
    k_loss<<<1, 256, 0, stream>>>(ce, out);
}